// Round 4
// baseline (253.532 us; speedup 1.0000x reference)
//
#include <hip/hip_runtime.h>

// LightweightConv1d: y[b,t,c] = sum_k softmax(w)[c%H,k] * x[b, t+k-PAD, c]
// x: (B,T,C) fp32 contiguous (C innermost), w: (H,1,K) fp32, y: (B,T,C) fp32.
// Compulsory traffic 268 MB -> ~43 us at 6.3 TB/s.
// R4 post-mortem: 92.5 us; latency-bound (VGPR=68 halved waves, 2048 blocks).
// R5 post-mortem: occupancy fixed (76%, VGPR 24) but SLOWER than R2 (80.7 vs
//   ~71 us), hbm 2.49 TB/s. Two findings: (a) float2=8B/lane halves bytes per
//   memory transaction vs float4 -> request-stream inefficiency at equal MLP;
//   (b) VGPR=24 < win[14]'s 28 proves the compiler SANK the batch loads toward
//   uses -- the 14-deep MLP never existed as written (same in R4: 68 < 88).
//   FETCH=65MB confirms L3/L2 absorb halo + half of x; amp is a non-issue.
// R6: float4 everywhere (16B/lane sweet spot), TCHUNK=8/W=14, XCD remap (each
//   XCD owns one full image b -> t-sequential stream, halo hits its L2), nt
//   stores kept, and asm keep-alive fence pinning all 14 loads issued up-front
//   (compiler cannot sink them; ~100 VGPR live; (256,4) cap 128 -> 16 waves/CU).

constexpr int B_   = 8;
constexpr int T_   = 4096;
constexpr int C_   = 1024;
constexpr int H_   = 16;
constexpr int K_   = 7;
constexpr int PAD_ = 3;
constexpr int TCHUNK = 8;             // outputs per thread along T
constexpr int W_  = TCHUNK + K_ - 1;  // 14 input rows per chunk
constexpr int C4  = C_ / 4;           // 256 float4 per row == blockDim.x
constexpr int NCHUNK = T_ / TCHUNK;   // 512 chunks per batch image
constexpr int NXCD = 8;

typedef float vfloat4 __attribute__((ext_vector_type(4)));  // native, nt-storable

__global__ __launch_bounds__(256, 4) void lwconv_kernel(
    const float* __restrict__ x, const float* __restrict__ w,
    float* __restrict__ y) {
  __shared__ float ws[H_][K_];
  const int tid = threadIdx.x;

  // Per-head softmax over K (112 values; threads 0..15 each do one head).
  if (tid < H_) {
    float v[K_];
    float m = -1e30f;
#pragma unroll
    for (int k = 0; k < K_; ++k) { v[k] = w[tid * K_ + k]; m = fmaxf(m, v[k]); }
    float s = 0.f;
#pragma unroll
    for (int k = 0; k < K_; ++k) { v[k] = expf(v[k] - m); s += v[k]; }
    const float inv = 1.f / s;
#pragma unroll
    for (int k = 0; k < K_; ++k) ws[tid][k] = v[k] * inv;
  }
  __syncthreads();

  // XCD-aware remap: hw round-robins consecutive blockIdx across the 8 XCDs.
  // grid=4096, cpx=512 -> XCD i owns wids [i*512,(i+1)*512) = ALL t-chunks of
  // image b=i. Consecutive wids are t-adjacent (share 6-row/24KB halo) and run
  // on the same XCD close in time -> halo hits that XCD's L2.
  const int cpx = (B_ * NCHUNK) / NXCD;   // 512
  const int wid = ((int)blockIdx.x % NXCD) * cpx + (int)blockIdx.x / NXCD;
  const int b  = wid / NCHUNK;
  const int t0 = (wid % NCHUNK) * TCHUNK;

  // Thread handles 4 consecutive channels c = 4*tid .. 4*tid+3.
  const int h0 = (4 * tid) & (H_ - 1);
  float wr[4][K_];
#pragma unroll
  for (int j = 0; j < 4; ++j)
#pragma unroll
    for (int k = 0; k < K_; ++k) wr[j][k] = ws[h0 + j][k];

  const float4* __restrict__ xr =
      reinterpret_cast<const float4*>(x + (size_t)b * T_ * C_) + tid;
  vfloat4* __restrict__ yr =
      reinterpret_cast<vfloat4*>(y + (size_t)b * T_ * C_) + tid;

  const float4 z4 = make_float4(0.f, 0.f, 0.f, 0.f);

  // Batch-load all W_=14 rows. The asm keep-alives force every load ISSUED
  // here (compiler cannot sink them into the compute loop as R4/R5 showed it
  // does): 14 KB/wave genuinely in flight; s_waitcnt still drains incrementally.
  float4 win[W_];
#pragma unroll
  for (int i = 0; i < W_; ++i) {
    const int t = t0 - PAD_ + i;  // wave-uniform predicate -> scalar branch
    win[i] = (t >= 0 && t < T_) ? xr[(size_t)t * C4] : z4;
  }
#pragma unroll
  for (int i = 0; i < W_; ++i)
    asm volatile("" :: "v"(win[i].x), "v"(win[i].y), "v"(win[i].z), "v"(win[i].w));

#pragma unroll
  for (int tt = 0; tt < TCHUNK; ++tt) {
    float ax = 0.f, ay = 0.f, az = 0.f, aw = 0.f;
#pragma unroll
    for (int k = 0; k < K_; ++k) {
      ax = fmaf(win[tt + k].x, wr[0][k], ax);
      ay = fmaf(win[tt + k].y, wr[1][k], ay);
      az = fmaf(win[tt + k].z, wr[2][k], az);
      aw = fmaf(win[tt + k].w, wr[3][k], aw);
    }
    // y is written once, never read: nontemporal keeps x resident in L2/L3.
    vfloat4 out;
    out.x = ax; out.y = ay; out.z = az; out.w = aw;
    __builtin_nontemporal_store(out, yr + (size_t)(t0 + tt) * C4);
  }
}

extern "C" void kernel_launch(void* const* d_in, const int* in_sizes, int n_in,
                              void* d_out, int out_size, void* d_ws, size_t ws_size,
                              hipStream_t stream) {
  const float* x = (const float*)d_in[0];   // (B,T,C) fp32
  const float* w = (const float*)d_in[1];   // (H,1,K) fp32
  float* y = (float*)d_out;                 // (B,T,C) fp32

  const int grid = B_ * NCHUNK;             // 4096 blocks
  lwconv_kernel<<<grid, 256, 0, stream>>>(x, w, y);
}

// Round 5
// 241.969 us; speedup vs baseline: 1.0478x; 1.0478x over previous
//
#include <hip/hip_runtime.h>

// LightweightConv1d: y[b,t,c] = sum_k softmax(w)[c%H,k] * x[b, t+k-PAD, c]
// x: (B,T,C) fp32 contiguous (C innermost), w: (H,1,K) fp32, y: (B,T,C) fp32.
// Compulsory traffic 268 MB -> ~43 us at 6.3 TB/s.
// History: R2~79us / R4 92.5 / R5 80.7 / R6 97 (conv dispatch; fills ~153us are
//   harness-side). Plateau at ~80us across occupancies 46%..76% -> occupancy is
//   NOT binding. Invariant: burst structure (14 loads -> wait -> 8 compute) and
//   363 MB logical traffic (1.75x read amp) served at ~4.5 TB/s by L1/L2/L3.
//   R6 lesson: asm keep-alives caused REMATERIALIZATION (VGPR=48 < 84 needed)
//   -- compiler reloaded every row for compute; fences can't force MLP.
// R7: register rolling-window. Block = BT=32 t-rows x all 1024 ch; circular
//   win[16] (full unroll -> static indices, no movs); per step: 1 load (row
//   t+13 ahead, ~10-step latency slack) || 28 FMA || 1 nt store. Each x row
//   read ONCE per block: amp 1.75 -> 1.19 (logical 363 -> 293 MB), and the
//   request stream is paced (copy-like), not bursty. Grid 1024 = 4 blk/CU
//   exactly one generation. Keep XCD remap + nt stores; no keep-alives.

constexpr int B_   = 8;
constexpr int T_   = 4096;
constexpr int C_   = 1024;
constexpr int H_   = 16;
constexpr int K_   = 7;
constexpr int PAD_ = 3;
constexpr int BT   = 32;              // t-rows per block
constexpr int NB   = 16;              // circular buffer slots (pow2)
constexpr int C4   = C_ / 4;          // 256 float4 per row == blockDim.x
constexpr int NCHUNK = T_ / BT;       // 128 chunks per image
constexpr int NXCD = 8;

typedef float vfloat4 __attribute__((ext_vector_type(4)));  // native, nt-storable

// win 64 + wr 28 + ~15 misc ≈ 110 VGPR -> (256,4) cap 128, 16 waves/CU.
__global__ __launch_bounds__(256, 4) void lwconv_kernel(
    const float* __restrict__ x, const float* __restrict__ w,
    float* __restrict__ y) {
  __shared__ float ws[H_][K_];
  const int tid = threadIdx.x;

  // Per-head softmax over K (112 values; threads 0..15 each do one head).
  if (tid < H_) {
    float v[K_];
    float m = -1e30f;
#pragma unroll
    for (int k = 0; k < K_; ++k) { v[k] = w[tid * K_ + k]; m = fmaxf(m, v[k]); }
    float s = 0.f;
#pragma unroll
    for (int k = 0; k < K_; ++k) { v[k] = expf(v[k] - m); s += v[k]; }
    const float inv = 1.f / s;
#pragma unroll
    for (int k = 0; k < K_; ++k) ws[tid][k] = v[k] * inv;
  }
  __syncthreads();

  // XCD-aware remap: XCD i owns wids [i*128,(i+1)*128) = all chunks of image
  // b=i -> each XCD streams one image t-sequentially (L2-local halo, DRAM-
  // friendly sequential footprint).
  const int cpx = (B_ * NCHUNK) / NXCD;   // 128
  const int wid = ((int)blockIdx.x % NXCD) * cpx + (int)blockIdx.x / NXCD;
  const int b  = wid / NCHUNK;
  const int t0 = (wid % NCHUNK) * BT;

  // Thread handles 4 consecutive channels c = 4*tid .. 4*tid+3.
  const int h0 = (4 * tid) & (H_ - 1);
  float wr[4][K_];
#pragma unroll
  for (int j = 0; j < 4; ++j)
#pragma unroll
    for (int k = 0; k < K_; ++k) wr[j][k] = ws[h0 + j][k];

  const float4* __restrict__ xr =
      reinterpret_cast<const float4*>(x + (size_t)b * T_ * C_) + tid;
  vfloat4* __restrict__ yr =
      reinterpret_cast<vfloat4*>(y + (size_t)b * T_ * C_) + tid;

  const float4 z4 = make_float4(0.f, 0.f, 0.f, 0.f);

  // Prologue: fill all 16 slots with rows t0-3 .. t0+12 (slot s <- row t0-3+s).
  // Upper bound never trips here (t0+12 <= 4076 < T); lower only for t0=0.
  float4 win[NB];
#pragma unroll
  for (int s = 0; s < NB; ++s) {
    const int t = t0 - PAD_ + s;
    win[s] = (t >= 0) ? xr[(size_t)t * C4] : z4;
  }

  // Steady state: step t computes y row t0+t from slots (t..t+6)&15, then
  // refills the vacated slot (t&15) with row t0+13+t (used 10 steps later ->
  // latency hidden under ~10 steps of FMA across 16 waves/CU). 22 in-loop
  // loads + 16 prologue = 38 = BT+6 rows: each row fetched exactly once.
#pragma unroll
  for (int t = 0; t < BT; ++t) {
    float ax = 0.f, ay = 0.f, az = 0.f, aw = 0.f;
#pragma unroll
    for (int k = 0; k < K_; ++k) {
      const int s = (t + k) & (NB - 1);
      ax = fmaf(win[s].x, wr[0][k], ax);
      ay = fmaf(win[s].y, wr[1][k], ay);
      az = fmaf(win[s].z, wr[2][k], az);
      aw = fmaf(win[s].w, wr[3][k], aw);
    }
    vfloat4 out;
    out.x = ax; out.y = ay; out.z = az; out.w = aw;
    __builtin_nontemporal_store(out, yr + (size_t)(t0 + t) * C4);

    if (t < BT - 10) {                      // compile-time guard: 22 loads
      const int tr = t0 + (NB - PAD_) + t;  // row t0+13+t
      win[t & (NB - 1)] = (tr < T_) ? xr[(size_t)tr * C4] : z4;
    }
  }
}

extern "C" void kernel_launch(void* const* d_in, const int* in_sizes, int n_in,
                              void* d_out, int out_size, void* d_ws, size_t ws_size,
                              hipStream_t stream) {
  const float* x = (const float*)d_in[0];   // (B,T,C) fp32
  const float* w = (const float*)d_in[1];   // (H,1,K) fp32
  float* y = (float*)d_out;                 // (B,T,C) fp32

  const int grid = B_ * NCHUNK;             // 1024 blocks
  lwconv_kernel<<<grid, 256, 0, stream>>>(x, w, y);
}

// Round 7
// 230.816 us; speedup vs baseline: 1.0984x; 1.0483x over previous
//
#include <hip/hip_runtime.h>
#include <stdint.h>

// LightweightConv1d: y[b,t,c] = sum_k softmax(w)[c%H,k] * x[b, t+k-PAD, c]
// x: (B,T,C) fp32 contiguous (C innermost), w: (H,1,K) fp32, y: (B,T,C) fp32.
// Compulsory traffic 268 MB -> ~43 us at 6.3 TB/s. Harness fills ~156 us of
// every bench number; conv dispatch is the remainder.
// History (conv dispatch): R2 ~71-79 / R4 92.5 / R5 80.7 / R6 97 / R7 85.6 /
//   R8 WRONG RESULTS. R4/R5/R7: compiler strip-mines/remats register-batched
//   loads (VGPR_Count < window size each time) -> effective MLP shallow ->
//   latency-bound at ~2.5 TB/s while fills prove 6.6. R8 (asm loads into
//   "=v" registers + counted vmcnt): compiler treats asm outputs as ready at
//   the asm point; RA copies / reg-only consumers can read in-flight load
//   destinations -> absmax 1.71. Lesson: deep MLP via VGPR destinations fights
//   scheduler AND regalloc; unwinnable at HIP source level.
// R9: deep MLP via LDS destinations -- __builtin_amdgcn_global_load_lds
//   (width 16). Destination is LDS: no register liveness, nothing to
//   strip-mine or remat; 14 back-to-back issues guaranteed (m97 pattern).
//   Each wave stages the 1KB quarter-row its own lanes read later (no
//   cross-wave dep); vmcnt(0) + barrier drain is simple and correct.
//   56KB LDS/block -> 2 blocks/CU; inter-block overlap covers the burst.
//   Softmax moved to per-thread regs (drops ws[] LDS + one barrier).

constexpr int B_   = 8;
constexpr int T_   = 4096;
constexpr int C_   = 1024;
constexpr int H_   = 16;
constexpr int K_   = 7;
constexpr int PAD_ = 3;
constexpr int TCHUNK = 8;             // outputs per block along T
constexpr int W_  = TCHUNK + K_ - 1;  // 14 input rows staged per block
constexpr int NCHUNK = T_ / TCHUNK;   // 512 chunks per image
constexpr int NXCD = 8;

typedef float vfloat4 __attribute__((ext_vector_type(4)));
typedef const __attribute__((address_space(1))) unsigned int* gptr_u32;
typedef __attribute__((address_space(3))) unsigned int* lptr_u32;

__global__ __launch_bounds__(256, 2) void lwconv_kernel(
    const float* __restrict__ x, const float* __restrict__ w,
    float* __restrict__ y) {
  __shared__ float xs[W_][C_];          // 14 x 4KB = 56 KB
  const int tid = threadIdx.x;

  // Per-thread softmax for this thread's 4 heads (28 L1-broadcast loads;
  // no LDS, no barrier).
  const int h0 = (4 * tid) & (H_ - 1);
  float wr[4][K_];
#pragma unroll
  for (int j = 0; j < 4; ++j) {
    const int h = h0 + j;               // <= 15, never wraps (4 | 16)
    float v[K_];
    float m = -1e30f;
#pragma unroll
    for (int k = 0; k < K_; ++k) { v[k] = w[h * K_ + k]; m = fmaxf(m, v[k]); }
    float s = 0.f;
#pragma unroll
    for (int k = 0; k < K_; ++k) { v[k] = expf(v[k] - m); s += v[k]; }
    const float inv = 1.f / s;
#pragma unroll
    for (int k = 0; k < K_; ++k) wr[j][k] = v[k] * inv;
  }

  // XCD-aware remap: XCD i owns wids [i*512,(i+1)*512) = all chunks of image
  // b=i; consecutive wids are t-adjacent (share 6-row/24KB halo) -> halo
  // re-stages hit that XCD's L2.
  const int cpx = (B_ * NCHUNK) / NXCD;   // 512
  const int wid = ((int)blockIdx.x % NXCD) * cpx + (int)blockIdx.x / NXCD;
  const int b  = wid / NCHUNK;
  const int t0 = (wid % NCHUNK) * TCHUNK;

  const size_t base = (size_t)b * T_ * C_;
  const float* xg = x + base + 4 * tid;   // this lane's 16B column
  float*       yg = y + base + 4 * tid;

  // Edge rows (t<0 / t>=T): zero this thread's own 16B in those slots.
  // Each wave touches only its own quarter-row -> no cross-wave dependency.
  const vfloat4 z4 = {0.f, 0.f, 0.f, 0.f};
  if (t0 == 0) {
#pragma unroll
    for (int i = 0; i < PAD_; ++i)
      *reinterpret_cast<vfloat4*>(&xs[i][4 * tid]) = z4;
  }
  if (t0 == T_ - TCHUNK) {
#pragma unroll
    for (int i = W_ - PAD_; i < W_; ++i)
      *reinterpret_cast<vfloat4*>(&xs[i][4 * tid]) = z4;
  }

  // Stage 14 rows async into LDS: per wave, 14 back-to-back
  // global_load_lds_dwordx4 (1KB each, the wave's own quarter-row).
  // LDS dest = wave-uniform base + lane*16; global src = per-lane address.
  const int wq = tid >> 6;                // wave id 0..3
#pragma unroll
  for (int i = 0; i < W_; ++i) {
    const int t = t0 - PAD_ + i;          // wave-uniform bounds test
    if (t >= 0 && t < T_) {
      __builtin_amdgcn_global_load_lds(
          (gptr_u32)(xg + (size_t)t * C_),
          (lptr_u32)&xs[i][wq * 256], 16, 0, 0);
    }
  }

  // Drain staging, then compute. (Each wave reads only what it staged, but
  // keep the barrier as cheap insurance; compiler also auto-drains before it.)
  asm volatile("s_waitcnt vmcnt(0)" ::: "memory");
  __syncthreads();

#pragma unroll
  for (int tt = 0; tt < TCHUNK; ++tt) {
    float ax = 0.f, ay = 0.f, az = 0.f, aw = 0.f;
#pragma unroll
    for (int k = 0; k < K_; ++k) {
      const float4 v = *reinterpret_cast<const float4*>(&xs[tt + k][4 * tid]);
      ax = fmaf(v.x, wr[0][k], ax);
      ay = fmaf(v.y, wr[1][k], ay);
      az = fmaf(v.z, wr[2][k], az);
      aw = fmaf(v.w, wr[3][k], aw);
    }
    vfloat4 o;
    o.x = ax; o.y = ay; o.z = az; o.w = aw;
    // y never read: nt store keeps x resident in L2/L3.
    __builtin_nontemporal_store(
        o, reinterpret_cast<vfloat4*>(yg + (size_t)(t0 + tt) * C_));
  }
}

extern "C" void kernel_launch(void* const* d_in, const int* in_sizes, int n_in,
                              void* d_out, int out_size, void* d_ws, size_t ws_size,
                              hipStream_t stream) {
  const float* x = (const float*)d_in[0];   // (B,T,C) fp32
  const float* w = (const float*)d_in[1];   // (H,1,K) fp32
  float* y = (float*)d_out;                 // (B,T,C) fp32

  const int grid = B_ * NCHUNK;             // 4096 blocks
  lwconv_kernel<<<grid, 256, 0, stream>>>(x, w, y);
}